// Round 5
// baseline (423.753 us; speedup 1.0000x reference)
//
#include <hip/hip_runtime.h>
#include <math.h>

#define SEQ   2048
#define BATCH 32
#define HID   1024
#define RPW   32                        // seq rows per wave
#define WPB   4                         // waves per block (independent)
#define WAVES_PER_B  (SEQ / RPW)        // 64 partials per batch
#define BLOCKS_PER_B (WAVES_PER_B / WPB) // 16
#define NCH   WAVES_PER_B               // 64

// native vector type: __builtin_nontemporal_load accepts these (not HIP_vector_type)
typedef float vf4 __attribute__((ext_vector_type(4)));

// ---------------------------------------------------------------------------
// Fused kernel: wave-autonomous flash partial + last-block-per-batch combine.
// Phase 1 (per wave, no LDS/barriers): rows s0..s0+31 of batch b; lane owns
//   columns {4*(lane+64j)} j<4; dot via 6-step shuffle butterfly (wave-uniform
//   score -> divergence-free online-softmax, single exp per row); next-row
//   prefetch keeps 4 KB/wave in flight; rnn_out loads nontemporal.
// Phase 2: the last of the 16 blocks of batch b (device-scope atomic counter)
//   combines the 64 partials (256 KB, L2/L3-hot) and writes out[b].
// ---------------------------------------------------------------------------
__global__ __launch_bounds__(256) void attn_fused(
    const float* __restrict__ rnn_out,   // [S, B, H]
    const float* __restrict__ state,     // [2, 2, B, H/2]
    float* __restrict__ o_part,          // [B*NCH, H]
    float* __restrict__ m_part,          // [B*NCH]
    float* __restrict__ l_part,          // [B*NCH]
    int*   __restrict__ counters,        // [B], pre-zeroed
    float* __restrict__ out)             // [B, H]
{
    const int b     = blockIdx.x / BLOCKS_PER_B;
    const int slice = blockIdx.x % BLOCKS_PER_B;
    const int lane  = threadIdx.x & 63;
    const int wav   = threadIdx.x >> 6;
    const int wid   = slice * WPB + wav;       // 0..63
    const int s0    = wid * RPW;

    // merged[b][h] = state[1][h/512][b][h%512]; lane's 4 vf4 slices
    vf4 mrg[4];
    #pragma unroll
    for (int j = 0; j < 4; ++j) {
        const int h   = 4 * (lane + 64 * j);
        const int dir = h >> 9;
        const int k   = h & 511;
        mrg[j] = *(const vf4*)(state + ((size_t)(2 + dir) * BATCH + b) * 512 + k);
    }

    const size_t row_stride = (size_t)BATCH * HID;
    const float* base = rnn_out + ((size_t)s0 * BATCH + b) * HID + 4 * lane;

    vf4 cur[4], nxt[4];
    #pragma unroll
    for (int j = 0; j < 4; ++j)
        cur[j] = __builtin_nontemporal_load((const vf4*)(base + 256 * j));

    float m = -INFINITY, l = 0.f;
    vf4 acc[4];
    #pragma unroll
    for (int j = 0; j < 4; ++j) acc[j] = (vf4)(0.f);

    for (int i = 0; i < RPW; ++i) {
        if (i + 1 < RPW) {
            const float* nb = base + (size_t)(i + 1) * row_stride;
            #pragma unroll
            for (int j = 0; j < 4; ++j)
                nxt[j] = __builtin_nontemporal_load((const vf4*)(nb + 256 * j));
        }

        float d = 0.f;
        #pragma unroll
        for (int j = 0; j < 4; ++j) {
            const vf4 p = cur[j] * mrg[j];
            d += p.x + p.y + p.z + p.w;
        }
        #pragma unroll
        for (int off = 1; off < 64; off <<= 1)
            d += __shfl_xor(d, off, 64);       // all lanes hold the full dot

        if (d > m) {                           // wave-uniform branch
            const float alpha = __expf(m - d); // exp(-inf)=0 on first row
            l = l * alpha + 1.f;               // p == 1 exactly
            #pragma unroll
            for (int j = 0; j < 4; ++j)
                acc[j] = acc[j] * alpha + cur[j];
            m = d;
        } else {
            const float p = __expf(d - m);
            l += p;
            #pragma unroll
            for (int j = 0; j < 4; ++j)
                acc[j] += p * cur[j];
        }
        #pragma unroll
        for (int j = 0; j < 4; ++j) cur[j] = nxt[j];
    }

    float* op = o_part + (size_t)(b * NCH + wid) * HID + 4 * lane;
    #pragma unroll
    for (int j = 0; j < 4; ++j) *(vf4*)(op + 256 * j) = acc[j];
    if (lane == 0) {
        m_part[b * NCH + wid] = m;
        l_part[b * NCH + wid] = l;
    }

    // ---- last-block-done combine for this batch ----
    __threadfence();                           // release partial writes (device scope)
    __shared__ int is_last;
    if (threadIdx.x == 0)
        is_last = (atomicAdd(&counters[b], 1) == BLOCKS_PER_B - 1);
    __syncthreads();
    if (!is_last) return;
    __threadfence();                           // acquire other blocks' writes

    const float* mp = m_part + b * NCH;
    const float* lp = l_part + b * NCH;
    float M = -INFINITY;
    for (int c = 0; c < NCH; ++c) M = fmaxf(M, mp[c]);
    float L = 0.f;
    for (int c = 0; c < NCH; ++c) L += lp[c] * __expf(mp[c] - M);
    const float invL = 1.f / L;

    const int h = threadIdx.x * 4;             // 256 threads x 4 cols = 1024
    vf4 r = (vf4)(0.f);
    for (int c = 0; c < NCH; ++c) {
        const float w = __expf(mp[c] - M) * invL;
        r += w * *(const vf4*)(o_part + (size_t)(b * NCH + c) * HID + h);
    }
    *(vf4*)(out + (size_t)b * HID + h) = r;
}

extern "C" void kernel_launch(void* const* d_in, const int* in_sizes, int n_in,
                              void* d_out, int out_size, void* d_ws, size_t ws_size,
                              hipStream_t stream) {
    const float* rnn_out = (const float*)d_in[0];   // [2048, 32, 1024] f32
    const float* state   = (const float*)d_in[1];   // [2, 2, 32, 512]  f32
    float* out = (float*)d_out;                     // [32, 1024, 1]    f32

    // workspace: o_part 8 MiB | m_part 8 KiB | l_part 8 KiB | counters 128 B
    float* o_part = (float*)d_ws;
    float* m_part = (float*)((char*)d_ws + (size_t)BATCH * NCH * HID * 4);
    float* l_part = m_part + BATCH * NCH;
    int*   counters = (int*)(l_part + BATCH * NCH);

    hipMemsetAsync(counters, 0, BATCH * sizeof(int), stream);
    attn_fused<<<BATCH * BLOCKS_PER_B, 256, 0, stream>>>(
        rnn_out, state, o_part, m_part, l_part, counters, out);
}